// Round 9
// baseline (25.078 us; speedup 1.0000x reference)
//
#include <hip/hip_runtime.h>
#include <math.h>

// ---------------------------------------------------------------------------
// Z_exp = Tr(M rho^x4) = degree-4 poly in Bloch (x,y,z), 35 monomials.
// R8 lesson: compact (non-unrolled) chain code + many blocks cut the chain
// cost (I$/utilization theory confirmed). R9: fuse into ONE dispatch —
// every block runs the compact 8-phase chain (tid<256) into LDS, batch
// float4 prefetched before the chain, eval after the final barrier.
// Chain + eval arithmetic copied verbatim from R8 (same absmax).
// ---------------------------------------------------------------------------

struct cpx { float re, im; };

__device__ __forceinline__ cpx cmul(cpx a, cpx b) {
    return { a.re * b.re - a.im * b.im, a.re * b.im + a.im * b.re };
}

// ---- compile-time Pauli-string -> monomial grouping (data-independent) ----
struct MonoTab { unsigned char cnt[125]; unsigned char idx[125][24]; };

constexpr int mono_of(int p) {
    int a = 0, b = 0, c = 0;
    for (int k = 0; k < 4; ++k) {
        const int pk = (p >> (2 * k)) & 3;   // 0=I,1=X,2=Y,3=Z
        a += (pk == 1); b += (pk == 2); c += (pk == 3);
    }
    return (a * 5 + b) * 5 + c;
}
constexpr MonoTab build_tab() {
    MonoTab t{};
    for (int m = 0; m < 125; ++m) {
        t.cnt[m] = 0;
        for (int k = 0; k < 24; ++k) t.idx[m][k] = 0;
    }
    for (int p = 0; p < 256; ++p) {          // ascending p: fixed sum order
        const int m = mono_of(p);
        t.idx[m][t.cnt[m]++] = (unsigned char)p;
    }
    return t;
}
__constant__ const MonoTab TAB = build_tab();

__global__ __launch_bounds__(512) void fused_kernel(
    const float4* __restrict__ in, const float* __restrict__ w_U,
    const float* __restrict__ w_RXZX, const float* __restrict__ scale_p,
    const float* __restrict__ bias_p, float2* __restrict__ out, int B2)
{
    __shared__ cpx   R[24][2][2];    // RXZX 2x2 gates
    __shared__ float ISc[6], ISs[6]; // iSWAP cos/sin
    __shared__ cpx   L[6][16][16];   // 16x16 layer matrices
    __shared__ cpx   P1[3][16][16];  // tree level 1: L1L0, L3L2, L5L4
    __shared__ cpx   Dm[16][16];     // P1[1]*P1[0]
    __shared__ cpx   Wf[16][16];     // P1[2]*Dm
    __shared__ cpx   Mm[16][16];     // W^dag Z0 W
    __shared__ float cp[256];        // Pauli-basis coefficients
    __shared__ float cf[125];        // monomial coefficients

    const int tid = threadIdx.x;
    const int idx = blockIdx.x * 512 + tid;

    // prefetch batch data + scalars; latency hidden under the chain
    float4 f = make_float4(0.f, 0.f, 0.f, 0.f);
    if (idx < B2) f = in[idx];
    const float scale = scale_p[0], bias = bias_p[0];

    const int i = (tid >> 4) & 15, j = tid & 15;

    // ---- Phase 1: 2x2 RXZX gates + iSWAP params ----
    if (tid < 24) {
        const float ta = w_RXZX[tid * 3 + 0];
        const float tb = w_RXZX[tid * 3 + 1];
        const float tc = w_RXZX[tid * 3 + 2];
        float sa, ca, sb, cb, sc, cc;
        sincosf(0.5f * ta, &sa, &ca);
        sincosf(0.5f * tb, &sb, &cb);
        sincosf(0.5f * tc, &sc, &cc);
        // RX(t)=[[c,-is],[-is,c]], RZ(t)=diag(c-is,c+is); g = RX(a)RZ(b)RX(c)
        const cpx e0 = { cb, -sb };
        const cpx e1 = { cb,  sb };
        const cpx T00 = { e0.re * cc, e0.im * cc };
        const cpx T01 = { -e0.im * (-sc), e0.re * (-sc) };
        const cpx T10 = { -e1.im * (-sc), e1.re * (-sc) };
        const cpx T11 = { e1.re * cc, e1.im * cc };
        R[tid][0][0] = { ca * T00.re + sa * T10.im, ca * T00.im - sa * T10.re };
        R[tid][0][1] = { ca * T01.re + sa * T11.im, ca * T01.im - sa * T11.re };
        R[tid][1][0] = { sa * T00.im + ca * T10.re, -sa * T00.re + ca * T10.im };
        R[tid][1][1] = { sa * T01.im + ca * T11.re, -sa * T01.re + ca * T11.im };
    } else if (tid < 30) {
        const int l = tid - 24;
        float s, c;
        sincosf(w_U[l], &s, &c);
        ISc[l] = c;
        ISs[l] = s;
    }
    __syncthreads();

    // ---- Phase 2: L[l] = (GA on iSWAP pair) x (GB on complement pair) ----
    // PAIR byte per layer l: qa | qb<<2 | qr<<4 | qs<<6,
    // PAIRS=[(1,2),(1,3),(1,2),(1,3),(0,3),(0,2)]
    if (tid < 256) {
        for (int l = 0; l < 6; ++l) {
            const int code = (int)((0xD89C8DC98DC9ULL >> (8 * l)) & 0xFF);
            const int qa = code & 3, qb = (code >> 2) & 3;
            const int qr = (code >> 4) & 3, qs = (code >> 6) & 3;
            const int uAi = (((i >> (3 - qa)) & 1) << 1) | ((i >> (3 - qb)) & 1);
            const int uAj = (((j >> (3 - qa)) & 1) << 1) | ((j >> (3 - qb)) & 1);
            const int uBi = (((i >> (3 - qr)) & 1) << 1) | ((i >> (3 - qs)) & 1);
            const int uBj = (((j >> (3 - qr)) & 1) << 1) | ((j >> (3 - qs)) & 1);
            const int ra = l * 4 + qa, rb = l * 4 + qb;
            cpx ga;
            if (uAj == 0)      ga = cmul(R[ra][uAi >> 1][0], R[rb][uAi & 1][0]);
            else if (uAj == 3) ga = cmul(R[ra][uAi >> 1][1], R[rb][uAi & 1][1]);
            else {
                const cpx k1 = cmul(R[ra][uAi >> 1][0], R[rb][uAi & 1][1]);
                const cpx k2 = cmul(R[ra][uAi >> 1][1], R[rb][uAi & 1][0]);
                const cpx tc = (uAj == 1) ? k1 : k2;   // * cos
                const cpx ts = (uAj == 1) ? k2 : k1;   // * i sin
                const float c = ISc[l], s = ISs[l];
                ga.re = c * tc.re - s * ts.im;
                ga.im = c * tc.im + s * ts.re;
            }
            const cpx gb = cmul(R[l * 4 + qr][uBi >> 1][uBj >> 1],
                                R[l * 4 + qs][uBi & 1][uBj & 1]);
            L[l][i][j] = cmul(ga, gb);
        }
    }
    __syncthreads();

    // ---- Phase 3: tree level 1 — P1[m] = L[2m+1]*L[2m] ----
    if (tid < 256) {
        for (int m = 0; m < 3; ++m) {
            cpx acc = {0.f, 0.f};
            for (int k = 0; k < 16; ++k) {
                const cpx a = L[2 * m + 1][i][k];
                const cpx b = L[2 * m][k][j];
                acc.re += a.re * b.re - a.im * b.im;
                acc.im += a.re * b.im + a.im * b.re;
            }
            P1[m][i][j] = acc;
        }
    }
    __syncthreads();

    // ---- Phase 4: D = P1[1]*P1[0] ----
    if (tid < 256) {
        cpx acc = {0.f, 0.f};
        for (int k = 0; k < 16; ++k) {
            const cpx a = P1[1][i][k];
            const cpx b = P1[0][k][j];
            acc.re += a.re * b.re - a.im * b.im;
            acc.im += a.re * b.im + a.im * b.re;
        }
        Dm[i][j] = acc;
    }
    __syncthreads();

    // ---- Phase 5: W = P1[2]*D ----
    if (tid < 256) {
        cpx acc = {0.f, 0.f};
        for (int k = 0; k < 16; ++k) {
            const cpx a = P1[2][i][k];
            const cpx b = Dm[k][j];
            acc.re += a.re * b.re - a.im * b.im;
            acc.im += a.re * b.im + a.im * b.re;
        }
        Wf[i][j] = acc;
    }
    __syncthreads();

    // ---- Phase 6: M[i][j] = sum_k zk conj(W[k][i]) W[k][j] ----
    if (tid < 256) {
        cpx acc = {0.f, 0.f};
        for (int k = 0; k < 16; ++k) {
            const float zk = (k < 8) ? 1.f : -1.f;
            const cpx a = Wf[k][i];
            const cpx b = Wf[k][j];
            acc.re += zk * (a.re * b.re + a.im * b.im);   // conj(a)*b
            acc.im += zk * (a.re * b.im - a.im * b.re);
        }
        Mm[i][j] = acc;
    }
    __syncthreads();

    // ---- Phase 7: Pauli traces cp[p] = Tr(M*P_p)/16, p = tid ----
    if (tid < 256) {
        const int p = tid;
        float accre = 0.f;
        for (int col = 0; col < 16; ++col) {
            int row = 0;
            cpx val = {1.f, 0.f};
            for (int k = 0; k < 4; ++k) {
                const int pk = (p >> (6 - 2 * k)) & 3;
                const int b = (col >> (3 - k)) & 1;
                int rb = b;
                if (pk == 1) {
                    rb = b ^ 1;
                } else if (pk == 2) {
                    rb = b ^ 1;
                    const cpx fc = {0.f, b ? -1.f : 1.f};
                    val = cmul(val, fc);
                } else if (pk == 3) {
                    if (b) { val.re = -val.re; val.im = -val.im; }
                }
                row |= rb << (3 - k);
            }
            const cpx mv = Mm[col][row];
            accre += mv.re * val.re - mv.im * val.im;
        }
        cp[p] = accre * (1.f / 16.f);
    }
    __syncthreads();

    // ---- Phase 8: collapse via compile-time table (125 threads) ----
    if (tid < 125) {
        const int cnt = TAB.cnt[tid];
        float s = 0.f;
        for (int k = 0; k < cnt; ++k)          // ascending: deterministic
            s += cp[TAB.idx[tid][k]];
        cf[tid] = s;
    }
    __syncthreads();

    // ---- eval: 2 elements per thread from LDS coefficients ----
    if (idx >= B2) return;

    float2 res;
    #pragma unroll
    for (int e = 0; e < 2; ++e) {
        const float f0 = e ? f.z : f.x;
        const float f1 = e ? f.w : f.y;
        float s0, c0, s1, c1;
        sincosf(f0, &s0, &c0);
        sincosf(f1, &s1, &c1);
        const float x = s1 * c0, y = s1 * s0, z = c1;

        float xp[5], yp[5], zp[5];
        xp[0] = yp[0] = zp[0] = 1.f;
        #pragma unroll
        for (int k = 1; k < 5; ++k) {
            xp[k] = xp[k - 1] * x;
            yp[k] = yp[k - 1] * y;
            zp[k] = zp[k - 1] * z;
        }

        float Z = 0.f;
        #pragma unroll
        for (int a = 0; a <= 4; ++a)
            #pragma unroll
            for (int b = 0; b <= 4 - a; ++b)
                #pragma unroll
                for (int c = 0; c <= 4 - a - b; ++c)
                    Z = fmaf(cf[(a * 5 + b) * 5 + c], xp[a] * yp[b] * zp[c], Z);

        const float noise = 0.04472135954999579f * (Z * Z - 1.f) * 0.25f;
        const float v = scale * (Z + noise) + bias;
        if (e) res.y = v; else res.x = v;
    }
    out[idx] = res;
}

extern "C" void kernel_launch(void* const* d_in, const int* in_sizes, int n_in,
                              void* d_out, int out_size, void* d_ws, size_t ws_size,
                              hipStream_t stream) {
    const float* inputs  = (const float*)d_in[0];   // [B,2] f32
    const float* w_U     = (const float*)d_in[1];   // [6]
    const float* w_RXZX  = (const float*)d_in[2];   // [6,4,3]
    const float* scale_p = (const float*)d_in[3];   // [1]
    const float* bias_p  = (const float*)d_in[4];   // [1]
    float* out = (float*)d_out;

    const int B  = in_sizes[0] / 2;
    const int B2 = B / 2;                           // 2 elements per thread

    fused_kernel<<<(B2 + 511) / 512, 512, 0, stream>>>(
        (const float4*)inputs, w_U, w_RXZX, scale_p, bias_p, (float2*)out, B2);
}

// Round 10
// 23.708 us; speedup vs baseline: 1.0578x; 1.0578x over previous
//
#include <hip/hip_runtime.h>
#include <math.h>

// ---------------------------------------------------------------------------
// Z_exp = Tr(M rho^x4) = degree-4 poly in Bloch (x,y,z), 35 monomials.
// R9 decomposition: chain ~18-19us (dependent-LDS rolled loops), eval ~4us.
// R10: (1) chain inner loops batch independent LDS loads (3-matmul
// interleave, 2-acc k-split, unroll 4) to amortize ds_read latency;
// (2) asymmetric waves: tid<256 chain-only, tid>=256 own ALL eval elements
// (4 each) with coef-independent prep BEFORE the barriers (overlaps chain).
// ---------------------------------------------------------------------------

struct cpx { float re, im; };

__device__ __forceinline__ cpx cmul(cpx a, cpx b) {
    return { a.re * b.re - a.im * b.im, a.re * b.im + a.im * b.re };
}

// ---- compile-time Pauli-string -> monomial grouping (data-independent) ----
struct MonoTab { unsigned char cnt[125]; unsigned char idx[125][24]; };

constexpr int mono_of(int p) {
    int a = 0, b = 0, c = 0;
    for (int k = 0; k < 4; ++k) {
        const int pk = (p >> (2 * k)) & 3;   // 0=I,1=X,2=Y,3=Z
        a += (pk == 1); b += (pk == 2); c += (pk == 3);
    }
    return (a * 5 + b) * 5 + c;
}
constexpr MonoTab build_tab() {
    MonoTab t{};
    for (int m = 0; m < 125; ++m) {
        t.cnt[m] = 0;
        for (int k = 0; k < 24; ++k) t.idx[m][k] = 0;
    }
    for (int p = 0; p < 256; ++p) {          // ascending p: fixed sum order
        const int m = mono_of(p);
        t.idx[m][t.cnt[m]++] = (unsigned char)p;
    }
    return t;
}
__constant__ const MonoTab TAB = build_tab();

__global__ __launch_bounds__(512) void fused_kernel(
    const float2* __restrict__ in2, const float* __restrict__ w_U,
    const float* __restrict__ w_RXZX, const float* __restrict__ scale_p,
    const float* __restrict__ bias_p, float* __restrict__ out, int B /*elements*/)
{
    __shared__ cpx   R[24][2][2];    // RXZX 2x2 gates
    __shared__ float ISc[6], ISs[6]; // iSWAP cos/sin
    __shared__ cpx   L[6][16][16];   // 16x16 layer matrices
    __shared__ cpx   P1[3][16][16];  // tree level 1: L1L0, L3L2, L5L4
    __shared__ cpx   Dm[16][16];     // P1[1]*P1[0]
    __shared__ cpx   Wf[16][16];     // P1[2]*Dm
    __shared__ cpx   Mm[16][16];     // W^dag Z0 W
    __shared__ float cp[256];        // Pauli-basis coefficients
    __shared__ float cf[125];        // monomial coefficients

    const int tid = threadIdx.x;
    const int bid = blockIdx.x;
    const int i = (tid >> 4) & 15, j = tid & 15;

    // =====================================================================
    // EVAL WAVES (tid>=256): coef-independent prep BEFORE the chain barriers
    // 4 elements per thread; 1024 elements per block.
    // =====================================================================
    float xp[4][5], yp[4][5], zp[4][5];
    float scale = 0.f, bias = 0.f;
    const int et = tid - 256;
    const int g0 = bid * 1024 + et * 4;
    if (tid >= 256) {
        scale = scale_p[0];
        bias  = bias_p[0];
        float f0[4], f1[4];
        #pragma unroll
        for (int e = 0; e < 4; ++e) {
            const int g = g0 + e;
            float2 t = { 0.f, 0.f };
            if (g < B) t = in2[g];
            f0[e] = t.x; f1[e] = t.y;
        }
        #pragma unroll
        for (int e = 0; e < 4; ++e) {
            float s0, c0, s1, c1;
            sincosf(f0[e], &s0, &c0);
            sincosf(f1[e], &s1, &c1);
            const float x = s1 * c0, y = s1 * s0, z = c1;
            xp[e][0] = yp[e][0] = zp[e][0] = 1.f;
            #pragma unroll
            for (int k = 1; k < 5; ++k) {
                xp[e][k] = xp[e][k - 1] * x;
                yp[e][k] = yp[e][k - 1] * y;
                zp[e][k] = zp[e][k - 1] * z;
            }
        }
    }

    // =====================================================================
    // CHAIN (tid<256) — 8 phases, compact code, LDS-load batching
    // =====================================================================

    // ---- Phase 1: 2x2 RXZX gates + iSWAP params ----
    if (tid < 24) {
        const float ta = w_RXZX[tid * 3 + 0];
        const float tb = w_RXZX[tid * 3 + 1];
        const float tc = w_RXZX[tid * 3 + 2];
        float sa, ca, sb, cb, sc, cc;
        sincosf(0.5f * ta, &sa, &ca);
        sincosf(0.5f * tb, &sb, &cb);
        sincosf(0.5f * tc, &sc, &cc);
        // RX(t)=[[c,-is],[-is,c]], RZ(t)=diag(c-is,c+is); g = RX(a)RZ(b)RX(c)
        const cpx e0 = { cb, -sb };
        const cpx e1 = { cb,  sb };
        const cpx T00 = { e0.re * cc, e0.im * cc };
        const cpx T01 = { -e0.im * (-sc), e0.re * (-sc) };
        const cpx T10 = { -e1.im * (-sc), e1.re * (-sc) };
        const cpx T11 = { e1.re * cc, e1.im * cc };
        R[tid][0][0] = { ca * T00.re + sa * T10.im, ca * T00.im - sa * T10.re };
        R[tid][0][1] = { ca * T01.re + sa * T11.im, ca * T01.im - sa * T11.re };
        R[tid][1][0] = { sa * T00.im + ca * T10.re, -sa * T00.re + ca * T10.im };
        R[tid][1][1] = { sa * T01.im + ca * T11.re, -sa * T01.re + ca * T11.im };
    } else if (tid < 30) {
        const int l = tid - 24;
        float s, c;
        sincosf(w_U[l], &s, &c);
        ISc[l] = c;
        ISs[l] = s;
    }
    __syncthreads();

    // ---- Phase 2: L[l] = (GA on iSWAP pair) x (GB on complement pair) ----
    if (tid < 256) {
        for (int l = 0; l < 6; ++l) {
            const int code = (int)((0xD89C8DC98DC9ULL >> (8 * l)) & 0xFF);
            const int qa = code & 3, qb = (code >> 2) & 3;
            const int qr = (code >> 4) & 3, qs = (code >> 6) & 3;
            const int uAi = (((i >> (3 - qa)) & 1) << 1) | ((i >> (3 - qb)) & 1);
            const int uAj = (((j >> (3 - qa)) & 1) << 1) | ((j >> (3 - qb)) & 1);
            const int uBi = (((i >> (3 - qr)) & 1) << 1) | ((i >> (3 - qs)) & 1);
            const int uBj = (((j >> (3 - qr)) & 1) << 1) | ((j >> (3 - qs)) & 1);
            const int ra = l * 4 + qa, rb = l * 4 + qb;
            cpx ga;
            if (uAj == 0)      ga = cmul(R[ra][uAi >> 1][0], R[rb][uAi & 1][0]);
            else if (uAj == 3) ga = cmul(R[ra][uAi >> 1][1], R[rb][uAi & 1][1]);
            else {
                const cpx k1 = cmul(R[ra][uAi >> 1][0], R[rb][uAi & 1][1]);
                const cpx k2 = cmul(R[ra][uAi >> 1][1], R[rb][uAi & 1][0]);
                const cpx tc = (uAj == 1) ? k1 : k2;   // * cos
                const cpx ts = (uAj == 1) ? k2 : k1;   // * i sin
                const float c = ISc[l], s = ISs[l];
                ga.re = c * tc.re - s * ts.im;
                ga.im = c * tc.im + s * ts.re;
            }
            const cpx gb = cmul(R[l * 4 + qr][uBi >> 1][uBj >> 1],
                                R[l * 4 + qs][uBi & 1][uBj & 1]);
            L[l][i][j] = cmul(ga, gb);
        }
    }
    __syncthreads();

    // ---- Phase 3: P1[m]=L[2m+1]*L[2m], 3 matmuls interleaved (6 loads/iter)
    if (tid < 256) {
        cpx a0 = {0.f, 0.f}, a1 = {0.f, 0.f}, a2 = {0.f, 0.f};
        #pragma unroll 4
        for (int k = 0; k < 16; ++k) {
            const cpx u1 = L[1][i][k], v0 = L[0][k][j];
            const cpx u3 = L[3][i][k], v2 = L[2][k][j];
            const cpx u5 = L[5][i][k], v4 = L[4][k][j];
            a0.re += u1.re * v0.re - u1.im * v0.im;
            a0.im += u1.re * v0.im + u1.im * v0.re;
            a1.re += u3.re * v2.re - u3.im * v2.im;
            a1.im += u3.re * v2.im + u3.im * v2.re;
            a2.re += u5.re * v4.re - u5.im * v4.im;
            a2.im += u5.re * v4.im + u5.im * v4.re;
        }
        P1[0][i][j] = a0; P1[1][i][j] = a1; P1[2][i][j] = a2;
    }
    __syncthreads();

    // ---- Phase 4: D = P1[1]*P1[0], 2-acc k-split (4 loads/iter) ----
    if (tid < 256) {
        cpx s0 = {0.f, 0.f}, s1 = {0.f, 0.f};
        #pragma unroll 4
        for (int k = 0; k < 8; ++k) {
            const cpx a = P1[1][i][k],     b = P1[0][k][j];
            const cpx c = P1[1][i][k + 8], d = P1[0][k + 8][j];
            s0.re += a.re * b.re - a.im * b.im;
            s0.im += a.re * b.im + a.im * b.re;
            s1.re += c.re * d.re - c.im * d.im;
            s1.im += c.re * d.im + c.im * d.re;
        }
        Dm[i][j] = { s0.re + s1.re, s0.im + s1.im };
    }
    __syncthreads();

    // ---- Phase 5: W = P1[2]*D ----
    if (tid < 256) {
        cpx s0 = {0.f, 0.f}, s1 = {0.f, 0.f};
        #pragma unroll 4
        for (int k = 0; k < 8; ++k) {
            const cpx a = P1[2][i][k],     b = Dm[k][j];
            const cpx c = P1[2][i][k + 8], d = Dm[k + 8][j];
            s0.re += a.re * b.re - a.im * b.im;
            s0.im += a.re * b.im + a.im * b.re;
            s1.re += c.re * d.re - c.im * d.im;
            s1.im += c.re * d.im + c.im * d.re;
        }
        Wf[i][j] = { s0.re + s1.re, s0.im + s1.im };
    }
    __syncthreads();

    // ---- Phase 6: M[i][j] = sum_k zk conj(W[k][i]) W[k][j] ----
    if (tid < 256) {
        cpx s0 = {0.f, 0.f}, s1 = {0.f, 0.f};
        #pragma unroll 4
        for (int k = 0; k < 8; ++k) {
            const cpx a = Wf[k][i],     b = Wf[k][j];       // zk=+1
            const cpx c = Wf[k + 8][i], d = Wf[k + 8][j];   // zk=-1
            s0.re += a.re * b.re + a.im * b.im;
            s0.im += a.re * b.im - a.im * b.re;
            s1.re += c.re * d.re + c.im * d.im;
            s1.im += c.re * d.im - c.im * d.re;
        }
        Mm[i][j] = { s0.re - s1.re, s0.im - s1.im };
    }
    __syncthreads();

    // ---- Phase 7: Pauli traces cp[p] = Tr(M*P_p)/16, p = tid ----
    if (tid < 256) {
        const int p = tid;
        float accre = 0.f;
        #pragma unroll 4
        for (int col = 0; col < 16; ++col) {
            int row = 0;
            cpx val = {1.f, 0.f};
            #pragma unroll
            for (int k = 0; k < 4; ++k) {
                const int pk = (p >> (6 - 2 * k)) & 3;
                const int b = (col >> (3 - k)) & 1;
                int rb = b;
                if (pk == 1) {
                    rb = b ^ 1;
                } else if (pk == 2) {
                    rb = b ^ 1;
                    const cpx fc = {0.f, b ? -1.f : 1.f};
                    val = cmul(val, fc);
                } else if (pk == 3) {
                    if (b) { val.re = -val.re; val.im = -val.im; }
                }
                row |= rb << (3 - k);
            }
            const cpx mv = Mm[col][row];
            accre += mv.re * val.re - mv.im * val.im;
        }
        cp[p] = accre * (1.f / 16.f);
    }
    __syncthreads();

    // ---- Phase 8: collapse via compile-time table (125 threads) ----
    if (tid < 125) {
        const int cnt = TAB.cnt[tid];
        float s = 0.f;
        #pragma unroll 4
        for (int k = 0; k < cnt; ++k)          // ascending: deterministic
            s += cp[TAB.idx[tid][k]];
        cf[tid] = s;
    }
    __syncthreads();

    // =====================================================================
    // EVAL FINISH (tid>=256): 35 coefficient FMAs x 4 elements, then store
    // =====================================================================
    if (tid < 256) return;

    float r[4] = { 0.f, 0.f, 0.f, 0.f };
    #pragma unroll
    for (int a = 0; a <= 4; ++a)
        #pragma unroll
        for (int b = 0; b <= 4 - a; ++b)
            #pragma unroll
            for (int c = 0; c <= 4 - a - b; ++c) {
                const float cv = cf[(a * 5 + b) * 5 + c];
                #pragma unroll
                for (int e = 0; e < 4; ++e)
                    r[e] = fmaf(cv, xp[e][a] * yp[e][b] * zp[e][c], r[e]);
            }

    #pragma unroll
    for (int e = 0; e < 4; ++e) {
        const float Z = r[e];
        const float noise = 0.04472135954999579f * (Z * Z - 1.f) * 0.25f;
        r[e] = scale * (Z + noise) + bias;
    }

    if (g0 + 3 < B) {
        *(float4*)&out[g0] = make_float4(r[0], r[1], r[2], r[3]);
    } else {
        #pragma unroll
        for (int e = 0; e < 4; ++e)
            if (g0 + e < B) out[g0 + e] = r[e];
    }
}

extern "C" void kernel_launch(void* const* d_in, const int* in_sizes, int n_in,
                              void* d_out, int out_size, void* d_ws, size_t ws_size,
                              hipStream_t stream) {
    const float* inputs  = (const float*)d_in[0];   // [B,2] f32
    const float* w_U     = (const float*)d_in[1];   // [6]
    const float* w_RXZX  = (const float*)d_in[2];   // [6,4,3]
    const float* scale_p = (const float*)d_in[3];   // [1]
    const float* bias_p  = (const float*)d_in[4];   // [1]
    float* out = (float*)d_out;

    const int B = in_sizes[0] / 2;                  // elements
    const int nblocks = (B + 1023) / 1024;          // 1024 elements per block

    fused_kernel<<<nblocks, 512, 0, stream>>>(
        (const float2*)inputs, w_U, w_RXZX, scale_p, bias_p, out, B);
}